// Round 1
// baseline (598.517 us; speedup 1.0000x reference)
//
#include <hip/hip_runtime.h>

#define NN 40000
#define NE 640000
#define D 128

typedef __attribute__((ext_vector_type(8))) short short8;
typedef __attribute__((ext_vector_type(4))) float f32x4;

__device__ __forceinline__ short f2b(float v) {
  unsigned int u = __builtin_bit_cast(unsigned int, v);
  u = (u + 0x7fffu + ((u >> 16) & 1u)) >> 16;
  return (short)u;
}
__device__ __forceinline__ float b2f(short s) {
  unsigned int u = ((unsigned int)(unsigned short)s) << 16;
  return __builtin_bit_cast(float, u);
}

// ---------------- K0: transpose + bf16-convert weights ----------------
// WnT/WaT: bf16, [c][k] layout (so MFMA B-frags load 8 contiguous k).
// Wg split into hi/lo bf16 for split-precision GEMM in K4.
__global__ __launch_bounds__(256) void k_prep(
    const float* __restrict__ Wn, const float* __restrict__ Wg,
    const float* __restrict__ Wa, short* __restrict__ WnT,
    short* __restrict__ WgThi, short* __restrict__ WgTlo,
    short* __restrict__ WaT) {
  int i = blockIdx.x * 256 + threadIdx.x;  // 0..16383
  int k = i >> 7, c = i & 127;
  WnT[c * D + k] = f2b(Wn[k * D + c]);
  WaT[c * D + k] = f2b(Wa[k * D + c]);
  float v = Wg[k * D + c];
  short hi = f2b(v);
  WgThi[c * D + k] = hi;
  WgTlo[c * D + k] = f2b(v - b2f(hi));
}

// ---------------- K1: node transform ----------------
// Per block: 64 rows. wave w -> rows [r0+16w, r0+16w+16).
// A-frag: lane l holds row (l&15), k = kt*32 + (l>>4)*8 + j  (j=0..7)
// B-frag: lane l holds col (l&15), same k slots -> permutation-safe.
// C/D: col = lane&15, row = (lane>>4)*4 + reg   [HW-verified]
__global__ __launch_bounds__(256) void k_node(
    const float* __restrict__ x, const short* __restrict__ WaT,
    const short* __restrict__ WnT, const float* __restrict__ ba,
    float* __restrict__ xn_out, short* __restrict__ h_out) {
  int r0 = blockIdx.x * 64;
  int w = threadIdx.x >> 6, l = threadIdx.x & 63;
  int g = l >> 4, c16 = l & 15;
  int rowA = r0 + w * 16 + c16;

  short8 a[4];
#pragma unroll
  for (int kt = 0; kt < 4; ++kt) {
    const float* p = x + rowA * D + kt * 32 + g * 8;
    f32x4 v0 = *(const f32x4*)p;
    f32x4 v1 = *(const f32x4*)(p + 4);
    short8 t;
    t[0] = f2b(v0[0]); t[1] = f2b(v0[1]); t[2] = f2b(v0[2]); t[3] = f2b(v0[3]);
    t[4] = f2b(v1[0]); t[5] = f2b(v1[1]); t[6] = f2b(v1[2]); t[7] = f2b(v1[3]);
    a[kt] = t;
  }

  // x @ Wa
  f32x4 acc[8];
#pragma unroll
  for (int ct = 0; ct < 8; ++ct) {
    f32x4 c = {0.f, 0.f, 0.f, 0.f};
#pragma unroll
    for (int kt = 0; kt < 4; ++kt) {
      short8 b = *(const short8*)(WaT + (ct * 16 + c16) * D + kt * 32 + g * 8);
      c = __builtin_amdgcn_mfma_f32_16x16x32_bf16(a[kt], b, c, 0, 0, 0);
    }
    acc[ct] = c;
  }
  // h = x * sigmoid(t + ba), store bf16
#pragma unroll
  for (int ct = 0; ct < 8; ++ct) {
    int cc = ct * 16 + c16;
    float bav = ba[cc];
#pragma unroll
    for (int r = 0; r < 4; ++r) {
      int rr = r0 + w * 16 + g * 4 + r;
      float t = acc[ct][r] + bav;
      float al = 1.0f / (1.0f + __expf(-t));
      float xv = x[rr * D + cc];
      h_out[rr * D + cc] = f2b(xv * al);
    }
  }
  // xn = x @ Wn  (bias added in K4), store fp32 into d_out
#pragma unroll
  for (int ct = 0; ct < 8; ++ct) {
    f32x4 c = {0.f, 0.f, 0.f, 0.f};
#pragma unroll
    for (int kt = 0; kt < 4; ++kt) {
      short8 b = *(const short8*)(WnT + (ct * 16 + c16) * D + kt * 32 + g * 8);
      c = __builtin_amdgcn_mfma_f32_16x16x32_bf16(a[kt], b, c, 0, 0, 0);
    }
    int cc = ct * 16 + c16;
#pragma unroll
    for (int r = 0; r < 4; ++r) {
      int rr = r0 + w * 16 + g * 4 + r;
      xn_out[rr * D + cc] = c[r];
    }
  }
}

// ---------------- K3: edge scatter (segment_sum) ----------------
// One wave per edge: gather h[col] (bf16 row, 4B/lane), atomic-add into s[row].
__global__ __launch_bounds__(256) void k_scatter(
    const int* __restrict__ ei, const short* __restrict__ h,
    float* __restrict__ s) {
  int l = threadIdx.x & 63;
  int wid = blockIdx.x * 4 + (threadIdx.x >> 6);
  int nw = gridDim.x * 4;
  for (int e = wid; e < NE; e += nw) {
    int r = ei[e];        // row (destination)
    int c = ei[NE + e];   // col (source)
    unsigned int hv = *(const unsigned int*)(h + c * D + 2 * l);
    float f0 = b2f((short)(hv & 0xffffu));
    float f1 = b2f((short)(hv >> 16));
    float* dst = s + r * D + 2 * l;
    unsafeAtomicAdd(dst, f0);
    unsafeAtomicAdd(dst + 1, f1);
  }
}

// ---------------- K4: out = tanh(xn + s @ Wg (split bf16) + bn + bg) -------
__global__ __launch_bounds__(256) void k_final(
    const float* __restrict__ s, const short* __restrict__ WgThi,
    const short* __restrict__ WgTlo, const float* __restrict__ bn,
    const float* __restrict__ bg, float* __restrict__ out) {
  int r0 = blockIdx.x * 64;
  int w = threadIdx.x >> 6, l = threadIdx.x & 63;
  int g = l >> 4, c16 = l & 15;
  int rowA = r0 + w * 16 + c16;

  short8 ahi[4], alo[4];
#pragma unroll
  for (int kt = 0; kt < 4; ++kt) {
    const float* p = s + rowA * D + kt * 32 + g * 8;
    f32x4 v0 = *(const f32x4*)p;
    f32x4 v1 = *(const f32x4*)(p + 4);
    short8 hi, lo;
#pragma unroll
    for (int j = 0; j < 4; ++j) {
      short hh = f2b(v0[j]);
      hi[j] = hh;
      lo[j] = f2b(v0[j] - b2f(hh));
    }
#pragma unroll
    for (int j = 0; j < 4; ++j) {
      short hh = f2b(v1[j]);
      hi[4 + j] = hh;
      lo[4 + j] = f2b(v1[j] - b2f(hh));
    }
    ahi[kt] = hi;
    alo[kt] = lo;
  }

#pragma unroll
  for (int ct = 0; ct < 8; ++ct) {
    f32x4 c = {0.f, 0.f, 0.f, 0.f};
#pragma unroll
    for (int kt = 0; kt < 4; ++kt) {
      const short* bp = WgThi + (ct * 16 + c16) * D + kt * 32 + g * 8;
      const short* lp = WgTlo + (ct * 16 + c16) * D + kt * 32 + g * 8;
      short8 bh = *(const short8*)bp;
      short8 bl = *(const short8*)lp;
      c = __builtin_amdgcn_mfma_f32_16x16x32_bf16(ahi[kt], bh, c, 0, 0, 0);
      c = __builtin_amdgcn_mfma_f32_16x16x32_bf16(alo[kt], bh, c, 0, 0, 0);
      c = __builtin_amdgcn_mfma_f32_16x16x32_bf16(ahi[kt], bl, c, 0, 0, 0);
    }
    int cc = ct * 16 + c16;
    float bias = bn[cc] + bg[cc];
#pragma unroll
    for (int r = 0; r < 4; ++r) {
      int rr = r0 + w * 16 + g * 4 + r;
      float z = c[r] + out[rr * D + cc] + bias;  // out currently holds xn
      out[rr * D + cc] = tanhf(z);
    }
  }
}

extern "C" void kernel_launch(void* const* d_in, const int* in_sizes, int n_in,
                              void* d_out, int out_size, void* d_ws,
                              size_t ws_size, hipStream_t stream) {
  const float* x = (const float*)d_in[0];
  const int* ei = (const int*)d_in[1];
  const float* Wn_w = (const float*)d_in[2];
  const float* Wn_b = (const float*)d_in[3];
  const float* Wg_w = (const float*)d_in[4];
  const float* Wg_b = (const float*)d_in[5];
  const float* Wa_w = (const float*)d_in[6];
  const float* Wa_b = (const float*)d_in[7];

  char* ws = (char*)d_ws;
  short* WaT = (short*)(ws + 0);
  short* WnT = (short*)(ws + 32 * 1024);
  short* WgThi = (short*)(ws + 64 * 1024);
  short* WgTlo = (short*)(ws + 96 * 1024);
  float* s = (float*)(ws + 128 * 1024);
  short* h = (short*)(ws + 128 * 1024 + (size_t)NN * D * 4);
  float* out = (float*)d_out;

  hipMemsetAsync(s, 0, (size_t)NN * D * sizeof(float), stream);
  k_prep<<<64, 256, 0, stream>>>(Wn_w, Wg_w, Wa_w, WnT, WgThi, WgTlo, WaT);
  k_node<<<NN / 64, 256, 0, stream>>>(x, WaT, WnT, Wa_b, out, h);
  k_scatter<<<4096, 256, 0, stream>>>(ei, h, s);
  k_final<<<NN / 64, 256, 0, stream>>>(s, WgThi, WgTlo, Wn_b, Wg_b, out);
}

// Round 2
// 150.407 us; speedup vs baseline: 3.9793x; 3.9793x over previous
//
#include <hip/hip_runtime.h>

#define NN 40000
#define NE 640000
#define D 128
#define CAP 64  // bucket capacity; P(Poisson(16) >= 64) ~ 3e-22

typedef __attribute__((ext_vector_type(8))) short short8;
typedef __attribute__((ext_vector_type(4))) float f32x4;

__device__ __forceinline__ short f2b(float v) {
  unsigned int u = __builtin_bit_cast(unsigned int, v);
  u = (u + 0x7fffu + ((u >> 16) & 1u)) >> 16;
  return (short)u;
}
__device__ __forceinline__ float b2f(short s) {
  unsigned int u = ((unsigned int)(unsigned short)s) << 16;
  return __builtin_bit_cast(float, u);
}

// ---------------- K0: transpose + bf16-convert weights ----------------
__global__ __launch_bounds__(256) void k_prep(
    const float* __restrict__ Wn, const float* __restrict__ Wg,
    const float* __restrict__ Wa, short* __restrict__ WnT,
    short* __restrict__ WgThi, short* __restrict__ WgTlo,
    short* __restrict__ WaT) {
  int i = blockIdx.x * 256 + threadIdx.x;  // 0..16383
  int k = i >> 7, c = i & 127;
  WnT[c * D + k] = f2b(Wn[k * D + c]);
  WaT[c * D + k] = f2b(Wa[k * D + c]);
  float v = Wg[k * D + c];
  short hi = f2b(v);
  WgThi[c * D + k] = hi;
  WgTlo[c * D + k] = f2b(v - b2f(hi));
}

// ---------------- K1: node transform ----------------
// A-frag: lane l holds row (l&15), k = kt*32 + (l>>4)*8 + j
// B-frag: lane l holds col (l&15), same k slots -> permutation-safe.
// C/D: col = lane&15, row = (lane>>4)*4 + reg
__global__ __launch_bounds__(256) void k_node(
    const float* __restrict__ x, const short* __restrict__ WaT,
    const short* __restrict__ WnT, const float* __restrict__ ba,
    float* __restrict__ xn_out, short* __restrict__ h_out) {
  int r0 = blockIdx.x * 64;
  int w = threadIdx.x >> 6, l = threadIdx.x & 63;
  int g = l >> 4, c16 = l & 15;
  int rowA = r0 + w * 16 + c16;

  short8 a[4];
#pragma unroll
  for (int kt = 0; kt < 4; ++kt) {
    const float* p = x + rowA * D + kt * 32 + g * 8;
    f32x4 v0 = *(const f32x4*)p;
    f32x4 v1 = *(const f32x4*)(p + 4);
    short8 t;
    t[0] = f2b(v0[0]); t[1] = f2b(v0[1]); t[2] = f2b(v0[2]); t[3] = f2b(v0[3]);
    t[4] = f2b(v1[0]); t[5] = f2b(v1[1]); t[6] = f2b(v1[2]); t[7] = f2b(v1[3]);
    a[kt] = t;
  }

  // x @ Wa
  f32x4 acc[8];
#pragma unroll
  for (int ct = 0; ct < 8; ++ct) {
    f32x4 c = {0.f, 0.f, 0.f, 0.f};
#pragma unroll
    for (int kt = 0; kt < 4; ++kt) {
      short8 b = *(const short8*)(WaT + (ct * 16 + c16) * D + kt * 32 + g * 8);
      c = __builtin_amdgcn_mfma_f32_16x16x32_bf16(a[kt], b, c, 0, 0, 0);
    }
    acc[ct] = c;
  }
  // h = x * sigmoid(t + ba), store bf16
#pragma unroll
  for (int ct = 0; ct < 8; ++ct) {
    int cc = ct * 16 + c16;
    float bav = ba[cc];
#pragma unroll
    for (int r = 0; r < 4; ++r) {
      int rr = r0 + w * 16 + g * 4 + r;
      float t = acc[ct][r] + bav;
      float al = 1.0f / (1.0f + __expf(-t));
      float xv = x[rr * D + cc];
      h_out[rr * D + cc] = f2b(xv * al);
    }
  }
  // xn = x @ Wn (bias added in K4), store fp32 into d_out
#pragma unroll
  for (int ct = 0; ct < 8; ++ct) {
    f32x4 c = {0.f, 0.f, 0.f, 0.f};
#pragma unroll
    for (int kt = 0; kt < 4; ++kt) {
      short8 b = *(const short8*)(WnT + (ct * 16 + c16) * D + kt * 32 + g * 8);
      c = __builtin_amdgcn_mfma_f32_16x16x32_bf16(a[kt], b, c, 0, 0, 0);
    }
    int cc = ct * 16 + c16;
#pragma unroll
    for (int r = 0; r < 4; ++r) {
      int rr = r0 + w * 16 + g * 4 + r;
      xn_out[rr * D + cc] = c[r];
    }
  }
}

// ---------------- K2: bucket fill (replaces per-element atomics) ----------
__global__ __launch_bounds__(256) void k_fill(
    const int* __restrict__ ei, int* __restrict__ cnt,
    int* __restrict__ bucket) {
  int e = blockIdx.x * 256 + threadIdx.x;
  if (e >= NE) return;
  int r = ei[e];       // destination row
  int c = ei[NE + e];  // source col
  int slot = atomicAdd(&cnt[r], 1);
  if (slot < CAP) bucket[r * CAP + slot] = c;
}

// ---------------- K3: gather-aggregate (no atomics) ----------------
// One wave per node: sum h[col] rows into f32 regs, one coalesced store.
__global__ __launch_bounds__(256) void k_aggr(
    const int* __restrict__ cnt, const int* __restrict__ bucket,
    const short* __restrict__ h, float* __restrict__ s) {
  int l = threadIdx.x & 63;
  int n = blockIdx.x * 4 + (threadIdx.x >> 6);
  if (n >= NN) return;
  int deg = cnt[n];
  deg = deg < CAP ? deg : CAP;
  int bc = bucket[n * CAP + l];  // lane-preloaded edge list (unused lanes: junk, never selected)
  float a0 = 0.f, a1 = 0.f;
  for (int j = 0; j < deg; ++j) {
    int c = __shfl(bc, j);
    unsigned int hv = *(const unsigned int*)(h + (size_t)c * D + 2 * l);
    a0 += b2f((short)(hv & 0xffffu));
    a1 += b2f((short)(hv >> 16));
  }
  s[n * D + 2 * l] = a0;
  s[n * D + 2 * l + 1] = a1;
}

// ---------------- K4: out = tanh(xn + s @ Wg (split bf16) + bn + bg) -------
__global__ __launch_bounds__(256) void k_final(
    const float* __restrict__ s, const short* __restrict__ WgThi,
    const short* __restrict__ WgTlo, const float* __restrict__ bn,
    const float* __restrict__ bg, float* __restrict__ out) {
  int r0 = blockIdx.x * 64;
  int w = threadIdx.x >> 6, l = threadIdx.x & 63;
  int g = l >> 4, c16 = l & 15;
  int rowA = r0 + w * 16 + c16;

  short8 ahi[4], alo[4];
#pragma unroll
  for (int kt = 0; kt < 4; ++kt) {
    const float* p = s + rowA * D + kt * 32 + g * 8;
    f32x4 v0 = *(const f32x4*)p;
    f32x4 v1 = *(const f32x4*)(p + 4);
    short8 hi, lo;
#pragma unroll
    for (int j = 0; j < 4; ++j) {
      short hh = f2b(v0[j]);
      hi[j] = hh;
      lo[j] = f2b(v0[j] - b2f(hh));
    }
#pragma unroll
    for (int j = 0; j < 4; ++j) {
      short hh = f2b(v1[j]);
      hi[4 + j] = hh;
      lo[4 + j] = f2b(v1[j] - b2f(hh));
    }
    ahi[kt] = hi;
    alo[kt] = lo;
  }

#pragma unroll
  for (int ct = 0; ct < 8; ++ct) {
    f32x4 c = {0.f, 0.f, 0.f, 0.f};
#pragma unroll
    for (int kt = 0; kt < 4; ++kt) {
      const short* bp = WgThi + (ct * 16 + c16) * D + kt * 32 + g * 8;
      const short* lp = WgTlo + (ct * 16 + c16) * D + kt * 32 + g * 8;
      short8 bh = *(const short8*)bp;
      short8 bl = *(const short8*)lp;
      c = __builtin_amdgcn_mfma_f32_16x16x32_bf16(ahi[kt], bh, c, 0, 0, 0);
      c = __builtin_amdgcn_mfma_f32_16x16x32_bf16(alo[kt], bh, c, 0, 0, 0);
      c = __builtin_amdgcn_mfma_f32_16x16x32_bf16(ahi[kt], bl, c, 0, 0, 0);
    }
    int cc = ct * 16 + c16;
    float bias = bn[cc] + bg[cc];
#pragma unroll
    for (int r = 0; r < 4; ++r) {
      int rr = r0 + w * 16 + g * 4 + r;
      float z = c[r] + out[rr * D + cc] + bias;  // out currently holds xn
      out[rr * D + cc] = tanhf(z);
    }
  }
}

extern "C" void kernel_launch(void* const* d_in, const int* in_sizes, int n_in,
                              void* d_out, int out_size, void* d_ws,
                              size_t ws_size, hipStream_t stream) {
  const float* x = (const float*)d_in[0];
  const int* ei = (const int*)d_in[1];
  const float* Wn_w = (const float*)d_in[2];
  const float* Wn_b = (const float*)d_in[3];
  const float* Wg_w = (const float*)d_in[4];
  const float* Wg_b = (const float*)d_in[5];
  const float* Wa_w = (const float*)d_in[6];
  const float* Wa_b = (const float*)d_in[7];

  char* ws = (char*)d_ws;
  short* WaT = (short*)(ws + 0);
  short* WnT = (short*)(ws + 32 * 1024);
  short* WgThi = (short*)(ws + 64 * 1024);
  short* WgTlo = (short*)(ws + 96 * 1024);
  int* cnt = (int*)(ws + 128 * 1024);              // 160 KB
  float* s = (float*)(ws + 512 * 1024);            // 20.48 MB
  short* h = (short*)(ws + 512 * 1024 + (size_t)NN * D * 4);  // 10.24 MB
  int* bucket = (int*)(ws + 512 * 1024 + (size_t)NN * D * 6); // 10.24 MB
  float* out = (float*)d_out;

  hipMemsetAsync(cnt, 0, (size_t)NN * sizeof(int), stream);
  k_prep<<<64, 256, 0, stream>>>(Wn_w, Wg_w, Wa_w, WnT, WgThi, WgTlo, WaT);
  k_node<<<NN / 64, 256, 0, stream>>>(x, WaT, WnT, Wa_b, out, h);
  k_fill<<<(NE + 255) / 256, 256, 0, stream>>>(ei, cnt, bucket);
  k_aggr<<<NN / 4, 256, 0, stream>>>(cnt, bucket, h, s);
  k_final<<<NN / 64, 256, 0, stream>>>(s, WgThi, WgTlo, Wn_b, Wg_b, out);
}

// Round 3
// 128.918 us; speedup vs baseline: 4.6426x; 1.1667x over previous
//
#include <hip/hip_runtime.h>

#define NN 40000
#define NE 640000
#define D 128
#define CAP 64  // bucket capacity; P(Poisson(16) >= 64) ~ 3e-22

typedef __attribute__((ext_vector_type(8))) short short8;
typedef __attribute__((ext_vector_type(4))) float f32x4;

__device__ __forceinline__ short f2b(float v) {
  unsigned int u = __builtin_bit_cast(unsigned int, v);
  u = (u + 0x7fffu + ((u >> 16) & 1u)) >> 16;
  return (short)u;
}
__device__ __forceinline__ float b2f(short s) {
  unsigned int u = ((unsigned int)(unsigned short)s) << 16;
  return __builtin_bit_cast(float, u);
}

// ---------------- K0: transpose + bf16-convert weights ----------------
__global__ __launch_bounds__(256) void k_prep(
    const float* __restrict__ Wn, const float* __restrict__ Wg,
    const float* __restrict__ Wa, short* __restrict__ WnT,
    short* __restrict__ WgThi, short* __restrict__ WgTlo,
    short* __restrict__ WaT) {
  int i = blockIdx.x * 256 + threadIdx.x;  // 0..16383
  int k = i >> 7, c = i & 127;
  WnT[c * D + k] = f2b(Wn[k * D + c]);
  WaT[c * D + k] = f2b(Wa[k * D + c]);
  float v = Wg[k * D + c];
  short hi = f2b(v);
  WgThi[c * D + k] = hi;
  WgTlo[c * D + k] = f2b(v - b2f(hi));
}

// ---------------- K1: node transform (16 rows/block, 2 ct per wave) -------
// A-frag: lane l holds row (l&15), k = kt*32 + (l>>4)*8 + j
// B-frag: lane l holds col (l&15), same k slots -> permutation-safe.
// C/D: col = lane&15, row = (lane>>4)*4 + reg
__global__ __launch_bounds__(256) void k_node(
    const float* __restrict__ x, const short* __restrict__ WaT,
    const short* __restrict__ WnT, const float* __restrict__ ba,
    float* __restrict__ xn_out, short* __restrict__ h_out) {
  int r0 = blockIdx.x * 16;
  int w = threadIdx.x >> 6, l = threadIdx.x & 63;
  int g = l >> 4, c16 = l & 15;
  int rowA = r0 + c16;

  short8 a[4];
#pragma unroll
  for (int kt = 0; kt < 4; ++kt) {
    const float* p = x + (size_t)rowA * D + kt * 32 + g * 8;
    f32x4 v0 = *(const f32x4*)p;
    f32x4 v1 = *(const f32x4*)(p + 4);
    short8 t;
    t[0] = f2b(v0[0]); t[1] = f2b(v0[1]); t[2] = f2b(v0[2]); t[3] = f2b(v0[3]);
    t[4] = f2b(v1[0]); t[5] = f2b(v1[1]); t[6] = f2b(v1[2]); t[7] = f2b(v1[3]);
    a[kt] = t;
  }

#pragma unroll
  for (int u = 0; u < 2; ++u) {
    int ct = w * 2 + u;
    int cc = ct * 16 + c16;
    // x @ Wa -> sigmoid -> h (bf16)
    f32x4 c = {0.f, 0.f, 0.f, 0.f};
#pragma unroll
    for (int kt = 0; kt < 4; ++kt) {
      short8 b = *(const short8*)(WaT + (size_t)cc * D + kt * 32 + g * 8);
      c = __builtin_amdgcn_mfma_f32_16x16x32_bf16(a[kt], b, c, 0, 0, 0);
    }
    float bav = ba[cc];
#pragma unroll
    for (int r = 0; r < 4; ++r) {
      int rr = r0 + g * 4 + r;
      float t = c[r] + bav;
      float al = 1.0f / (1.0f + __expf(-t));
      float xv = x[(size_t)rr * D + cc];
      h_out[(size_t)rr * D + cc] = f2b(xv * al);
    }
    // x @ Wn -> xn (f32, staged in d_out)
    f32x4 cn = {0.f, 0.f, 0.f, 0.f};
#pragma unroll
    for (int kt = 0; kt < 4; ++kt) {
      short8 b = *(const short8*)(WnT + (size_t)cc * D + kt * 32 + g * 8);
      cn = __builtin_amdgcn_mfma_f32_16x16x32_bf16(a[kt], b, cn, 0, 0, 0);
    }
#pragma unroll
    for (int r = 0; r < 4; ++r) {
      int rr = r0 + g * 4 + r;
      xn_out[(size_t)rr * D + cc] = cn[r];
    }
  }
}

// ---------------- K2: bucket fill ----------------
__global__ __launch_bounds__(256) void k_fill(
    const int* __restrict__ ei, int* __restrict__ cnt,
    int* __restrict__ bucket) {
  int e = blockIdx.x * 256 + threadIdx.x;
  if (e >= NE) return;
  int r = ei[e];       // destination row
  int c = ei[NE + e];  // source col
  int slot = atomicAdd(&cnt[r], 1);
  if (slot < CAP) bucket[r * CAP + slot] = c;
}

// ---------------- K3: gather-aggregate, 4 neighbors/iter, MLP=8 -----------
// One wave per node. Lane l: group g=l>>4 handles neighbor j+g, chunk i=l&15
// covers channels [i*8, i*8+8). Group-reduce via shfl_xor(16,32).
__global__ __launch_bounds__(256) void k_aggr(
    const int* __restrict__ cnt, const int* __restrict__ bucket,
    const short* __restrict__ h, float* __restrict__ s) {
  int l = threadIdx.x & 63;
  int n = blockIdx.x * 4 + (threadIdx.x >> 6);
  if (n >= NN) return;
  int g = l >> 4, i = l & 15;
  int deg = cnt[n];
  deg = deg < CAP ? deg : CAP;
  int bc = bucket[n * CAP + l];  // slot l's col (junk for l>=deg, never used)
  float acc[8];
#pragma unroll
  for (int q = 0; q < 8; ++q) acc[q] = 0.f;

  int j = 0;
  for (; j + 8 <= deg; j += 8) {
    int c0 = __shfl(bc, j + g);
    int c1 = __shfl(bc, j + 4 + g);
    short8 v0 = *(const short8*)(h + (size_t)c0 * D + i * 8);
    short8 v1 = *(const short8*)(h + (size_t)c1 * D + i * 8);
#pragma unroll
    for (int q = 0; q < 8; ++q) acc[q] += b2f(v0[q]);
#pragma unroll
    for (int q = 0; q < 8; ++q) acc[q] += b2f(v1[q]);
  }
  for (; j < deg; j += 4) {
    int src = j + g;
    int clamped = src < deg ? src : deg - 1;
    int c0 = __shfl(bc, clamped);
    if (src < deg) {
      short8 v0 = *(const short8*)(h + (size_t)c0 * D + i * 8);
#pragma unroll
      for (int q = 0; q < 8; ++q) acc[q] += b2f(v0[q]);
    }
  }

#pragma unroll
  for (int q = 0; q < 8; ++q) {
    acc[q] += __shfl_xor(acc[q], 16);
    acc[q] += __shfl_xor(acc[q], 32);
  }
  if (g == 0) {
    f32x4 lo = {acc[0], acc[1], acc[2], acc[3]};
    f32x4 hi = {acc[4], acc[5], acc[6], acc[7]};
    *(f32x4*)(s + (size_t)n * D + i * 8) = lo;
    *(f32x4*)(s + (size_t)n * D + i * 8 + 4) = hi;
  }
}

// ---------------- K4: out = tanh(xn + s @ Wg (split bf16) + bn + bg) -------
// 16 rows/block, 2 ct per wave -> grid 2500, occupancy fix.
__global__ __launch_bounds__(256) void k_final(
    const float* __restrict__ s, const short* __restrict__ WgThi,
    const short* __restrict__ WgTlo, const float* __restrict__ bn,
    const float* __restrict__ bg, float* __restrict__ out) {
  int r0 = blockIdx.x * 16;
  int w = threadIdx.x >> 6, l = threadIdx.x & 63;
  int g = l >> 4, c16 = l & 15;
  int rowA = r0 + c16;

  short8 ahi[4], alo[4];
#pragma unroll
  for (int kt = 0; kt < 4; ++kt) {
    const float* p = s + (size_t)rowA * D + kt * 32 + g * 8;
    f32x4 v0 = *(const f32x4*)p;
    f32x4 v1 = *(const f32x4*)(p + 4);
    short8 hi, lo;
#pragma unroll
    for (int jq = 0; jq < 4; ++jq) {
      short hh = f2b(v0[jq]);
      hi[jq] = hh;
      lo[jq] = f2b(v0[jq] - b2f(hh));
    }
#pragma unroll
    for (int jq = 0; jq < 4; ++jq) {
      short hh = f2b(v1[jq]);
      hi[4 + jq] = hh;
      lo[4 + jq] = f2b(v1[jq] - b2f(hh));
    }
    ahi[kt] = hi;
    alo[kt] = lo;
  }

#pragma unroll
  for (int u = 0; u < 2; ++u) {
    int ct = w * 2 + u;
    int cc = ct * 16 + c16;
    f32x4 c = {0.f, 0.f, 0.f, 0.f};
#pragma unroll
    for (int kt = 0; kt < 4; ++kt) {
      short8 bh = *(const short8*)(WgThi + (size_t)cc * D + kt * 32 + g * 8);
      short8 bl = *(const short8*)(WgTlo + (size_t)cc * D + kt * 32 + g * 8);
      c = __builtin_amdgcn_mfma_f32_16x16x32_bf16(ahi[kt], bh, c, 0, 0, 0);
      c = __builtin_amdgcn_mfma_f32_16x16x32_bf16(alo[kt], bh, c, 0, 0, 0);
      c = __builtin_amdgcn_mfma_f32_16x16x32_bf16(ahi[kt], bl, c, 0, 0, 0);
    }
    float bias = bn[cc] + bg[cc];
#pragma unroll
    for (int r = 0; r < 4; ++r) {
      int rr = r0 + g * 4 + r;
      float z = c[r] + out[(size_t)rr * D + cc] + bias;  // out holds xn
      out[(size_t)rr * D + cc] = tanhf(z);
    }
  }
}

extern "C" void kernel_launch(void* const* d_in, const int* in_sizes, int n_in,
                              void* d_out, int out_size, void* d_ws,
                              size_t ws_size, hipStream_t stream) {
  const float* x = (const float*)d_in[0];
  const int* ei = (const int*)d_in[1];
  const float* Wn_w = (const float*)d_in[2];
  const float* Wn_b = (const float*)d_in[3];
  const float* Wg_w = (const float*)d_in[4];
  const float* Wg_b = (const float*)d_in[5];
  const float* Wa_w = (const float*)d_in[6];
  const float* Wa_b = (const float*)d_in[7];

  char* ws = (char*)d_ws;
  short* WaT = (short*)(ws + 0);
  short* WnT = (short*)(ws + 32 * 1024);
  short* WgThi = (short*)(ws + 64 * 1024);
  short* WgTlo = (short*)(ws + 96 * 1024);
  int* cnt = (int*)(ws + 128 * 1024);                          // 160 KB
  float* s = (float*)(ws + 512 * 1024);                        // 20.48 MB
  short* h = (short*)(ws + 512 * 1024 + (size_t)NN * D * 4);   // 10.24 MB
  int* bucket = (int*)(ws + 512 * 1024 + (size_t)NN * D * 6);  // 10.24 MB
  float* out = (float*)d_out;

  hipMemsetAsync(cnt, 0, (size_t)NN * sizeof(int), stream);
  k_prep<<<64, 256, 0, stream>>>(Wn_w, Wg_w, Wa_w, WnT, WgThi, WgTlo, WaT);
  k_node<<<NN / 16, 256, 0, stream>>>(x, WaT, WnT, Wa_b, out, h);
  k_fill<<<(NE + 255) / 256, 256, 0, stream>>>(ei, cnt, bucket);
  k_aggr<<<NN / 4, 256, 0, stream>>>(cnt, bucket, h, s);
  k_final<<<NN / 16, 256, 0, stream>>>(s, WgThi, WgTlo, Wn_b, Wg_b, out);
}

// Round 4
// 126.371 us; speedup vs baseline: 4.7362x; 1.0201x over previous
//
#include <hip/hip_runtime.h>

#define NN 40000
#define NE 640000
#define D 128
#define CAP 64  // bucket capacity; P(Poisson(16) >= 64) ~ 3e-22

typedef __attribute__((ext_vector_type(8))) short short8;
typedef __attribute__((ext_vector_type(4))) float f32x4;
typedef __attribute__((ext_vector_type(4))) int i32x4;

__device__ __forceinline__ short f2b(float v) {
  unsigned int u = __builtin_bit_cast(unsigned int, v);
  u = (u + 0x7fffu + ((u >> 16) & 1u)) >> 16;
  return (short)u;
}
__device__ __forceinline__ float b2f(short s) {
  unsigned int u = ((unsigned int)(unsigned short)s) << 16;
  return __builtin_bit_cast(float, u);
}

// ---------------- K0: transpose + bf16-convert weights, zero cnt ----------
__global__ __launch_bounds__(256) void k_prep(
    const float* __restrict__ Wn, const float* __restrict__ Wg,
    const float* __restrict__ Wa, short* __restrict__ WnT,
    short* __restrict__ WgThi, short* __restrict__ WgTlo,
    short* __restrict__ WaT, int* __restrict__ cnt) {
  int i = blockIdx.x * 256 + threadIdx.x;  // 0..16383
  int k = i >> 7, c = i & 127;
  WnT[c * D + k] = f2b(Wn[k * D + c]);
  WaT[c * D + k] = f2b(Wa[k * D + c]);
  float v = Wg[k * D + c];
  short hi = f2b(v);
  WgThi[c * D + k] = hi;
  WgTlo[c * D + k] = f2b(v - b2f(hi));
  // zero cnt: 40000 ints = 10000 int4
  if (i < 10000) {
    i32x4 z = {0, 0, 0, 0};
    *(i32x4*)(cnt + i * 4) = z;
  }
}

// ---------------- K1: node transform (16 rows/block, 2 ct per wave) -------
// A-frag: lane l holds row (l&15), k = kt*32 + (l>>4)*8 + j
// B-frag: lane l holds col (l&15), same k slots -> permutation-safe.
// C/D: col = lane&15, row = (lane>>4)*4 + reg
__global__ __launch_bounds__(256) void k_node(
    const float* __restrict__ x, const short* __restrict__ WaT,
    const short* __restrict__ WnT, const float* __restrict__ ba,
    float* __restrict__ xn_out, short* __restrict__ h_out) {
  int r0 = blockIdx.x * 16;
  int w = threadIdx.x >> 6, l = threadIdx.x & 63;
  int g = l >> 4, c16 = l & 15;
  int rowA = r0 + c16;

  short8 a[4];
#pragma unroll
  for (int kt = 0; kt < 4; ++kt) {
    const float* p = x + (size_t)rowA * D + kt * 32 + g * 8;
    f32x4 v0 = *(const f32x4*)p;
    f32x4 v1 = *(const f32x4*)(p + 4);
    short8 t;
    t[0] = f2b(v0[0]); t[1] = f2b(v0[1]); t[2] = f2b(v0[2]); t[3] = f2b(v0[3]);
    t[4] = f2b(v1[0]); t[5] = f2b(v1[1]); t[6] = f2b(v1[2]); t[7] = f2b(v1[3]);
    a[kt] = t;
  }

#pragma unroll
  for (int u = 0; u < 2; ++u) {
    int ct = w * 2 + u;
    int cc = ct * 16 + c16;
    // x @ Wa -> sigmoid -> h (bf16)
    f32x4 c = {0.f, 0.f, 0.f, 0.f};
#pragma unroll
    for (int kt = 0; kt < 4; ++kt) {
      short8 b = *(const short8*)(WaT + (size_t)cc * D + kt * 32 + g * 8);
      c = __builtin_amdgcn_mfma_f32_16x16x32_bf16(a[kt], b, c, 0, 0, 0);
    }
    float bav = ba[cc];
#pragma unroll
    for (int r = 0; r < 4; ++r) {
      int rr = r0 + g * 4 + r;
      float t = c[r] + bav;
      float al = 1.0f / (1.0f + __expf(-t));
      float xv = x[(size_t)rr * D + cc];
      h_out[(size_t)rr * D + cc] = f2b(xv * al);
    }
    // x @ Wn -> xn (f32, staged in d_out)
    f32x4 cn = {0.f, 0.f, 0.f, 0.f};
#pragma unroll
    for (int kt = 0; kt < 4; ++kt) {
      short8 b = *(const short8*)(WnT + (size_t)cc * D + kt * 32 + g * 8);
      cn = __builtin_amdgcn_mfma_f32_16x16x32_bf16(a[kt], b, cn, 0, 0, 0);
    }
#pragma unroll
    for (int r = 0; r < 4; ++r) {
      int rr = r0 + g * 4 + r;
      xn_out[(size_t)rr * D + cc] = cn[r];
    }
  }
}

// ---------------- K2: bucket fill ----------------
__global__ __launch_bounds__(256) void k_fill(
    const int* __restrict__ ei, int* __restrict__ cnt,
    int* __restrict__ bucket) {
  int e = blockIdx.x * 256 + threadIdx.x;
  if (e >= NE) return;
  int r = ei[e];       // destination row
  int c = ei[NE + e];  // source col
  int slot = atomicAdd(&cnt[r], 1);
  if (slot < CAP) bucket[r * CAP + slot] = c;
}

// ---------------- K3: gather-aggregate, 4 neighbors/iter, MLP=8 -----------
// One wave per node. Lane l: group g=l>>4 handles neighbor j+g, chunk i=l&15
// covers channels [i*8, i*8+8). Group-reduce via shfl_xor(16,32).
__global__ __launch_bounds__(256) void k_aggr(
    const int* __restrict__ cnt, const int* __restrict__ bucket,
    const short* __restrict__ h, float* __restrict__ s) {
  int l = threadIdx.x & 63;
  int n = blockIdx.x * 4 + (threadIdx.x >> 6);
  if (n >= NN) return;
  int g = l >> 4, i = l & 15;
  int deg = cnt[n];
  deg = deg < CAP ? deg : CAP;
  int bc = bucket[n * CAP + l];  // slot l's col (junk for l>=deg, never used)
  float acc[8];
#pragma unroll
  for (int q = 0; q < 8; ++q) acc[q] = 0.f;

  int j = 0;
  for (; j + 8 <= deg; j += 8) {
    int c0 = __shfl(bc, j + g);
    int c1 = __shfl(bc, j + 4 + g);
    short8 v0 = *(const short8*)(h + (size_t)c0 * D + i * 8);
    short8 v1 = *(const short8*)(h + (size_t)c1 * D + i * 8);
#pragma unroll
    for (int q = 0; q < 8; ++q) acc[q] += b2f(v0[q]);
#pragma unroll
    for (int q = 0; q < 8; ++q) acc[q] += b2f(v1[q]);
  }
  for (; j < deg; j += 4) {
    int src = j + g;
    int clamped = src < deg ? src : deg - 1;
    int c0 = __shfl(bc, clamped);
    if (src < deg) {
      short8 v0 = *(const short8*)(h + (size_t)c0 * D + i * 8);
#pragma unroll
      for (int q = 0; q < 8; ++q) acc[q] += b2f(v0[q]);
    }
  }

#pragma unroll
  for (int q = 0; q < 8; ++q) {
    acc[q] += __shfl_xor(acc[q], 16);
    acc[q] += __shfl_xor(acc[q], 32);
  }
  if (g == 0) {
    f32x4 lo = {acc[0], acc[1], acc[2], acc[3]};
    f32x4 hi = {acc[4], acc[5], acc[6], acc[7]};
    *(f32x4*)(s + (size_t)n * D + i * 8) = lo;
    *(f32x4*)(s + (size_t)n * D + i * 8 + 4) = hi;
  }
}

// ---------------- K4: out = tanh(xn + s @ Wg (split bf16) + bn + bg) -------
__global__ __launch_bounds__(256) void k_final(
    const float* __restrict__ s, const short* __restrict__ WgThi,
    const short* __restrict__ WgTlo, const float* __restrict__ bn,
    const float* __restrict__ bg, float* __restrict__ out) {
  int r0 = blockIdx.x * 16;
  int w = threadIdx.x >> 6, l = threadIdx.x & 63;
  int g = l >> 4, c16 = l & 15;
  int rowA = r0 + c16;

  short8 ahi[4], alo[4];
#pragma unroll
  for (int kt = 0; kt < 4; ++kt) {
    const float* p = s + (size_t)rowA * D + kt * 32 + g * 8;
    f32x4 v0 = *(const f32x4*)p;
    f32x4 v1 = *(const f32x4*)(p + 4);
    short8 hi, lo;
#pragma unroll
    for (int jq = 0; jq < 4; ++jq) {
      short hh = f2b(v0[jq]);
      hi[jq] = hh;
      lo[jq] = f2b(v0[jq] - b2f(hh));
    }
#pragma unroll
    for (int jq = 0; jq < 4; ++jq) {
      short hh = f2b(v1[jq]);
      hi[4 + jq] = hh;
      lo[4 + jq] = f2b(v1[jq] - b2f(hh));
    }
    ahi[kt] = hi;
    alo[kt] = lo;
  }

#pragma unroll
  for (int u = 0; u < 2; ++u) {
    int ct = w * 2 + u;
    int cc = ct * 16 + c16;
    f32x4 c = {0.f, 0.f, 0.f, 0.f};
#pragma unroll
    for (int kt = 0; kt < 4; ++kt) {
      short8 bh = *(const short8*)(WgThi + (size_t)cc * D + kt * 32 + g * 8);
      short8 bl = *(const short8*)(WgTlo + (size_t)cc * D + kt * 32 + g * 8);
      c = __builtin_amdgcn_mfma_f32_16x16x32_bf16(ahi[kt], bh, c, 0, 0, 0);
      c = __builtin_amdgcn_mfma_f32_16x16x32_bf16(alo[kt], bh, c, 0, 0, 0);
      c = __builtin_amdgcn_mfma_f32_16x16x32_bf16(ahi[kt], bl, c, 0, 0, 0);
    }
    float bias = bn[cc] + bg[cc];
#pragma unroll
    for (int r = 0; r < 4; ++r) {
      int rr = r0 + g * 4 + r;
      float z = c[r] + out[(size_t)rr * D + cc] + bias;  // out holds xn
      out[(size_t)rr * D + cc] = tanhf(z);
    }
  }
}

extern "C" void kernel_launch(void* const* d_in, const int* in_sizes, int n_in,
                              void* d_out, int out_size, void* d_ws,
                              size_t ws_size, hipStream_t stream) {
  const float* x = (const float*)d_in[0];
  const int* ei = (const int*)d_in[1];
  const float* Wn_w = (const float*)d_in[2];
  const float* Wn_b = (const float*)d_in[3];
  const float* Wg_w = (const float*)d_in[4];
  const float* Wg_b = (const float*)d_in[5];
  const float* Wa_w = (const float*)d_in[6];
  const float* Wa_b = (const float*)d_in[7];

  char* ws = (char*)d_ws;
  short* WaT = (short*)(ws + 0);
  short* WnT = (short*)(ws + 32 * 1024);
  short* WgThi = (short*)(ws + 64 * 1024);
  short* WgTlo = (short*)(ws + 96 * 1024);
  int* cnt = (int*)(ws + 128 * 1024);                          // 160 KB
  float* s = (float*)(ws + 512 * 1024);                        // 20.48 MB
  short* h = (short*)(ws + 512 * 1024 + (size_t)NN * D * 4);   // 10.24 MB
  int* bucket = (int*)(ws + 512 * 1024 + (size_t)NN * D * 6);  // 10.24 MB
  float* out = (float*)d_out;

  k_prep<<<64, 256, 0, stream>>>(Wn_w, Wg_w, Wa_w, WnT, WgThi, WgTlo, WaT, cnt);
  k_node<<<NN / 16, 256, 0, stream>>>(x, WaT, WnT, Wa_b, out, h);
  k_fill<<<(NE + 255) / 256, 256, 0, stream>>>(ei, cnt, bucket);
  k_aggr<<<NN / 4, 256, 0, stream>>>(cnt, bucket, h, s);
  k_final<<<NN / 16, 256, 0, stream>>>(s, WgThi, WgTlo, Wn_b, Wg_b, out);
}